// Round 2
// baseline (373.031 us; speedup 1.0000x reference)
//
#include <hip/hip_runtime.h>
#include <hip/hip_fp16.h>
#include <hip/hip_cooperative_groups.h>
#include <math.h>

// SPAIRPointFeatureNetwork on MI355X.
//   h_{p,j} = Q[j] - G[p];  celu monotonic => segmax(celu(h)) = celu(max_j Q[j] - G[p]).
// Per-edge work = gather fp16 Q row + packed-fp16 running max.
//
// R7: 4 dispatches (edge+finish fused per layer), 177 us.
// R8: single cooperative kernel @1024 blocks -> launch FAILED silently (output
//     all zeros; hipLaunchCooperativeKernel return never checked; 1024 is
//     exactly 256CU x 4blk/CU, zero margin in the runtime's validation).
// R9 (this): grid-agnostic mega kernel (grid-stride over tiles). Launch
//     ladder: coop@1024 -> coop@512 -> classic 4-dispatch fallback. Return
//     codes checked; mode cached in a static so capture never sees a failed
//     attempt; sticky error cleared via hipGetLastError().

#define NPTS 65536
#define KNBR 64

namespace cg = cooperative_groups;

__device__ __forceinline__ float celu1(float x) {
    return x > 0.0f ? x : (__expf(x) - 1.0f);
}

__device__ __forceinline__ unsigned pkmax(unsigned a, unsigned b) {
    unsigned d;
    asm("v_pk_max_f16 %0, %1, %2" : "=v"(d) : "v"(a), "v"(b));
    return d;
}

__device__ __forceinline__ unsigned pack2(float a, float b) {
    __half2 h = __floats2half2_rn(a, b);
    return *(unsigned*)&h;
}

// One fused layer phase for a 64-point tile at pbase: edge gather+max ->
// m staged in LDS -> per-point finish. Block = 256 threads = 4 waves.
// Trailing __syncthreads so m_lds can be reused by the next tile/phase.
template <int FH, int FOUT, int FHN, bool WRITEX>
__device__ __forceinline__ void layer_phase(
    uint4* __restrict__ m_lds,       // 64 * (FH/8) uint4
    const __half* __restrict__ q,    // N x FH (fp16)
    const int* __restrict__ idx,     // N x 64 (int32)
    const float* __restrict__ pos,
    const float* __restrict__ wap,   // 3 x FH  (dpos rows of this layer's wa)
    const float* __restrict__ wb,    // FH x FOUT
    const float* __restrict__ bb,    // FOUT
    const float* __restrict__ wan,   // (FOUT+3) x FHN or null
    const float* __restrict__ ban,   // FHN or null
    float* __restrict__ xout,        // x region base (only if WRITEX)
    __half* __restrict__ qnext,      // N x FHN fp16 (only if FHN>0)
    int pbase)
{
    constexpr int SL  = FH / 8;      // 16B slice-lanes per row (1,2,4)
    constexpr int LPP = SL * 8;      // lanes per point (8,16,32)
    constexpr int PPW = 64 / LPP;    // points per wave per iter (8,4,2)
    constexpr int NIT = 64 / (4 * PPW);  // iters so block covers 64 points

    int w  = threadIdx.x >> 6;
    int l  = threadIdx.x & 63;
    int pl = l / LPP;
    int u  = l % LPP;
    int c  = u % SL;                 // 16B slice within row
    int g  = u / SL;                 // edge group 0..7 (8 edges each)

#pragma unroll
    for (int it = 0; it < NIT; ++it) {
        int lp = it * (4 * PPW) + w * PPW + pl;   // local point 0..63
        int p  = pbase + lp;
        const uint4* ip = (const uint4*)(idx + p * KNBR + g * 8);
        uint4 i0 = ip[0];
        uint4 i1 = ip[1];
        // 8 independent row-slice loads, all issued before first use
        uint4 v[8];
        v[0] = *(const uint4*)(q + (int)i0.x * FH + c * 8);
        v[1] = *(const uint4*)(q + (int)i0.y * FH + c * 8);
        v[2] = *(const uint4*)(q + (int)i0.z * FH + c * 8);
        v[3] = *(const uint4*)(q + (int)i0.w * FH + c * 8);
        v[4] = *(const uint4*)(q + (int)i1.x * FH + c * 8);
        v[5] = *(const uint4*)(q + (int)i1.y * FH + c * 8);
        v[6] = *(const uint4*)(q + (int)i1.z * FH + c * 8);
        v[7] = *(const uint4*)(q + (int)i1.w * FH + c * 8);

        unsigned ax = 0xFC00FC00u, ay = 0xFC00FC00u, az = 0xFC00FC00u, aw = 0xFC00FC00u;
#pragma unroll
        for (int k = 0; k < 8; ++k) {
            ax = pkmax(ax, v[k].x);
            ay = pkmax(ay, v[k].y);
            az = pkmax(az, v[k].z);
            aw = pkmax(aw, v[k].w);
        }
        // butterfly across the 8 edge groups (strides SL..4SL stay in-point)
#pragma unroll
        for (int st = SL; st < LPP; st <<= 1) {
            ax = pkmax(ax, (unsigned)__shfl_xor((int)ax, st, 64));
            ay = pkmax(ay, (unsigned)__shfl_xor((int)ay, st, 64));
            az = pkmax(az, (unsigned)__shfl_xor((int)az, st, 64));
            aw = pkmax(aw, (unsigned)__shfl_xor((int)aw, st, 64));
        }
        if (g == 0) {
            uint4 r; r.x = ax; r.y = ay; r.z = az; r.w = aw;
            m_lds[lp * SL + c] = r;
        }
    }
    __syncthreads();

    if constexpr (WRITEX) {
        // Final layer: 4 lanes per point, each computes 8 of FOUT=32 outputs.
        // Keeps live floats ~= FH + 8 instead of FH + FOUT (VGPR cap 128).
        int pt  = threadIdx.x >> 2;
        int qtr = threadIdx.x & 3;
        int p   = pbase + pt;
        float p0 = pos[3 * p + 0];
        float p1 = pos[3 * p + 1];
        float p2 = pos[3 * p + 2];

        float h[FH];
#pragma unroll
        for (int s = 0; s < SL; ++s) {
            uint4 vv = m_lds[pt * SL + s];
            unsigned w4[4] = {vv.x, vv.y, vv.z, vv.w};
#pragma unroll
            for (int k = 0; k < 4; ++k) {
                float2 f = __half22float2(*(__half2*)&w4[k]);
                h[s * 8 + k * 2 + 0] = f.x;
                h[s * 8 + k * 2 + 1] = f.y;
            }
        }
#pragma unroll
        for (int ch = 0; ch < FH; ++ch) {
            float gg = p0 * wap[ch] + p1 * wap[FH + ch] + p2 * wap[2 * FH + ch];
            h[ch] = celu1(h[ch] - gg);
        }
        float x[8];
#pragma unroll
        for (int j = 0; j < 8; ++j) {
            int c2 = qtr * 8 + j;
            float a = bb[c2];
#pragma unroll
            for (int ch = 0; ch < FH; ++ch)
                a = fmaf(h[ch], wb[ch * FOUT + c2], a);
            x[j] = celu1(a);
        }
        float4* xo = (float4*)(xout + (long long)p * FOUT + qtr * 8);
        xo[0] = make_float4(x[0], x[1], x[2], x[3]);
        xo[1] = make_float4(x[4], x[5], x[6], x[7]);
    } else if (threadIdx.x < 64) {
        int lt = threadIdx.x;
        int p  = pbase + lt;
        float p0 = pos[3 * p + 0];
        float p1 = pos[3 * p + 1];
        float p2 = pos[3 * p + 2];

        float h[FH];
#pragma unroll
        for (int s = 0; s < SL; ++s) {
            uint4 vv = m_lds[lt * SL + s];
            unsigned w4[4] = {vv.x, vv.y, vv.z, vv.w};
#pragma unroll
            for (int k = 0; k < 4; ++k) {
                float2 f = __half22float2(*(__half2*)&w4[k]);
                h[s * 8 + k * 2 + 0] = f.x;
                h[s * 8 + k * 2 + 1] = f.y;
            }
        }
#pragma unroll
        for (int ch = 0; ch < FH; ++ch) {
            float gg = p0 * wap[ch] + p1 * wap[FH + ch] + p2 * wap[2 * FH + ch];
            h[ch] = celu1(h[ch] - gg);
        }
        float x[FOUT];
#pragma unroll
        for (int c2 = 0; c2 < FOUT; ++c2) {
            float a = bb[c2];
#pragma unroll
            for (int ch = 0; ch < FH; ++ch)
                a = fmaf(h[ch], wb[ch * FOUT + c2], a);
            x[c2] = celu1(a);
        }
        if constexpr (FHN > 0) {
            // qnext packed 8-at-a-time: peak live floats = FOUT + 8.
            uint4* qo = (uint4*)(qnext + p * FHN);
#pragma unroll
            for (int s = 0; s < FHN / 8; ++s) {
                float qn[8];
#pragma unroll
                for (int k = 0; k < 8; ++k) {
                    int cn = s * 8 + k;
                    float a = ban[cn];
#pragma unroll
                    for (int c2 = 0; c2 < FOUT; ++c2)
                        a = fmaf(x[c2], wan[c2 * FHN + cn], a);
                    a = fmaf(p0, wan[(FOUT + 0) * FHN + cn], a);
                    a = fmaf(p1, wan[(FOUT + 1) * FHN + cn], a);
                    a = fmaf(p2, wan[(FOUT + 2) * FHN + cn], a);
                    qn[k] = a;
                }
                uint4 pk;
                pk.x = pack2(qn[0], qn[1]);
                pk.y = pack2(qn[2], qn[3]);
                pk.z = pack2(qn[4], qn[5]);
                pk.w = pack2(qn[6], qn[7]);
                qo[s] = pk;
            }
        }
    }
    __syncthreads();   // m_lds reusable by next tile / next phase
}

__device__ __forceinline__ void prep_body(
    int t, const float* __restrict__ pos,
    const float* __restrict__ w1a, const float* __restrict__ b1a,
    __half* __restrict__ q1, float* __restrict__ dout)
{
    float p0 = pos[3 * t + 0];
    float p1 = pos[3 * t + 1];
    float p2 = pos[3 * t + 2];
    dout[3 * t + 0] = p0;
    dout[3 * t + 1] = p1;
    dout[3 * t + 2] = p2;
    float qv[8];
#pragma unroll
    for (int c = 0; c < 8; ++c) {
        float a = b1a[c];
        a = fmaf(p0, w1a[0 * 8 + c] + w1a[3 * 8 + c], a);
        a = fmaf(p1, w1a[1 * 8 + c] + w1a[4 * 8 + c], a);
        a = fmaf(p2, w1a[2 * 8 + c] + w1a[5 * 8 + c], a);
        qv[c] = a;
    }
    uint4 pk;
    pk.x = pack2(qv[0], qv[1]);
    pk.y = pack2(qv[2], qv[3]);
    pk.z = pack2(qv[4], qv[5]);
    pk.w = pack2(qv[6], qv[7]);
    *(uint4*)(q1 + 8 * t) = pk;
}

// ---------------- cooperative mega kernel (grid-size agnostic) ----------------
__global__ __launch_bounds__(256, 4) void k_mega(
    const float* __restrict__ pos,
    const int* __restrict__ idx,
    const float* __restrict__ w1a, const float* __restrict__ b1a,
    const float* __restrict__ w1b, const float* __restrict__ b1b,
    const float* __restrict__ w2a, const float* __restrict__ b2a,
    const float* __restrict__ w2b, const float* __restrict__ b2b,
    const float* __restrict__ w3a, const float* __restrict__ b3a,
    const float* __restrict__ w3b, const float* __restrict__ b3b,
    __half* __restrict__ A, __half* __restrict__ B,
    float* __restrict__ out, int out_size)
{
    __shared__ uint4 m_lds[64 * 4];  // max SL=4 -> 4 KB, reused by all phases
    cg::grid_group grid = cg::this_grid();
    const int ntiles = NPTS / 64;
    const int gstride = gridDim.x * 256;
    int t0 = blockIdx.x * 256 + threadIdx.x;

    // ---- phase 0: prep (Q1 from pos, pos copy to out, zero batch tail) ----
    for (int t = t0; t < NPTS; t += gstride)
        prep_body(t, pos, w1a, b1a, A, out);
    for (int j = 35 * NPTS + t0; j < out_size; j += gstride)
        out[j] = 0.0f;
    grid.sync();

    // ---- layer 1: FH=8 -> FOUT=8, emits Q2 (16ch) into B ----
    for (int tb = blockIdx.x; tb < ntiles; tb += gridDim.x)
        layer_phase<8, 8, 16, false>(m_lds, A, idx, pos,
                                     w1a + 3 * 8, w1b, b1b, w2a, b2a,
                                     nullptr, B, tb * 64);
    grid.sync();

    // ---- layer 2: FH=16 -> FOUT=16, emits Q3 (32ch) into A ----
    for (int tb = blockIdx.x; tb < ntiles; tb += gridDim.x)
        layer_phase<16, 16, 32, false>(m_lds, B, idx, pos,
                                       w2a + 8 * 16, w2b, b2b, w3a, b3a,
                                       nullptr, A, tb * 64);
    grid.sync();

    // ---- layer 3: FH=32 -> FOUT=32, writes final x into out ----
    for (int tb = blockIdx.x; tb < ntiles; tb += gridDim.x)
        layer_phase<32, 32, 0, true>(m_lds, A, idx, pos,
                                     w3a + 16 * 32, w3b, b3b, nullptr, nullptr,
                                     out + 3 * NPTS, nullptr, tb * 64);
}

// ---------------- classic fallback kernels (R7 structure, proven) ----------------
__global__ __launch_bounds__(256) void k_prep(
    const float* __restrict__ pos,
    const float* __restrict__ w1a, const float* __restrict__ b1a,
    __half* __restrict__ q1, float* __restrict__ dout, int out_size)
{
    int t = blockIdx.x * 256 + threadIdx.x;
    if (t < NPTS)
        prep_body(t, pos, w1a, b1a, q1, dout);
    for (int j = 35 * NPTS + t; j < out_size; j += NPTS)
        dout[j] = 0.0f;
}

template <int FH, int FOUT, int FHN, bool WRITEX>
__global__ __launch_bounds__(256) void k_layer(
    const __half* __restrict__ q, const int* __restrict__ idx,
    const float* __restrict__ pos,
    const float* __restrict__ wap, const float* __restrict__ wb,
    const float* __restrict__ bb,
    const float* __restrict__ wan, const float* __restrict__ ban,
    float* __restrict__ xout, __half* __restrict__ qnext)
{
    __shared__ uint4 m_lds[64 * 4];
    layer_phase<FH, FOUT, FHN, WRITEX>(m_lds, q, idx, pos, wap, wb, bb,
                                       wan, ban, xout, qnext, blockIdx.x * 64);
}

extern "C" void kernel_launch(void* const* d_in, const int* in_sizes, int n_in,
                              void* d_out, int out_size, void* d_ws, size_t ws_size,
                              hipStream_t stream) {
    const float* pos = (const float*)d_in[0];
    // d_in[1] rgb (unused), d_in[2] batch (zeros), d_in[3] out_index
    const int* idx = (const int*)d_in[4];   // in_index, int32 per harness contract
    const float* w1a = (const float*)d_in[5];
    const float* b1a = (const float*)d_in[6];
    const float* w1b = (const float*)d_in[7];
    const float* b1b = (const float*)d_in[8];
    const float* w2a = (const float*)d_in[9];
    const float* b2a = (const float*)d_in[10];
    const float* w2b = (const float*)d_in[11];
    const float* b2b = (const float*)d_in[12];
    const float* w3a = (const float*)d_in[13];
    const float* b3a = (const float*)d_in[14];
    const float* w3b = (const float*)d_in[15];
    const float* b3b = (const float*)d_in[16];
    float* out = (float*)d_out;

    char* ws = (char*)d_ws;
    __half* A = (__half*)ws;                        // 4 MB max: Q1 (1MB) then Q3 (4MB)
    __half* B = (__half*)(ws + (4u << 20));         // 2 MB: Q2

    // mode: -1 undecided, 2 = coop@1024, 1 = coop@512, 0 = classic fallback.
    static int g_mode = -1;
    bool launched = false;

    if (g_mode != 0) {
        void* args[] = {
            (void*)&pos, (void*)&idx,
            (void*)&w1a, (void*)&b1a, (void*)&w1b, (void*)&b1b,
            (void*)&w2a, (void*)&b2a, (void*)&w2b, (void*)&b2b,
            (void*)&w3a, (void*)&b3a, (void*)&w3b, (void*)&b3b,
            (void*)&A, (void*)&B, (void*)&out, (void*)&out_size
        };
        if (g_mode == -1 || g_mode == 2) {
            hipError_t e = hipLaunchCooperativeKernel((const void*)k_mega,
                                                      dim3(1024), dim3(256),
                                                      args, 0, stream);
            if (e == hipSuccess) { g_mode = 2; launched = true; }
            else { (void)hipGetLastError(); if (g_mode == -1) g_mode = 1; else g_mode = 0; }
        }
        if (!launched && g_mode == 1) {
            hipError_t e = hipLaunchCooperativeKernel((const void*)k_mega,
                                                      dim3(512), dim3(256),
                                                      args, 0, stream);
            if (e == hipSuccess) { launched = true; }
            else { (void)hipGetLastError(); g_mode = 0; }
        }
    }

    if (!launched) {
        // classic 4-dispatch path (R7, proven correct & 177us)
        k_prep<<<NPTS / 256, 256, 0, stream>>>(pos, w1a, b1a, A, out, out_size);
        k_layer<8, 8, 16, false><<<NPTS / 64, 256, 0, stream>>>(
            A, idx, pos, w1a + 3 * 8, w1b, b1b, w2a, b2a, nullptr, B);
        k_layer<16, 16, 32, false><<<NPTS / 64, 256, 0, stream>>>(
            B, idx, pos, w2a + 8 * 16, w2b, b2b, w3a, b3a, nullptr, A);
        k_layer<32, 32, 0, true><<<NPTS / 64, 256, 0, stream>>>(
            A, idx, pos, w3a + 16 * 32, w3b, b3b, nullptr, nullptr,
            out + 3 * NPTS, nullptr);
    }
}

// Round 3
// 177.964 us; speedup vs baseline: 2.0961x; 2.0961x over previous
//
#include <hip/hip_runtime.h>
#include <hip/hip_fp16.h>
#include <math.h>

// SPAIRPointFeatureNetwork on MI355X.
//   h_{p,j} = Q[j] - G[p];  celu monotonic => segmax(celu(h)) = celu(max_j Q[j] - G[p]).
// Per-edge work = gather fp16 Q row + packed-fp16 running max.
//
// R7: 4 dispatches (edge+finish fused per layer), 64-pt tiles, 177 us.
// R8: coop mega @1024 failed to launch (zeros).
// R9: grid-agnostic coop mega launched -> 439 us. grid.sync() costs ~80-100us
//     each at 1024 blocks (VALUBusy 3%, HBM 2.6% => all spin). Coop is DEAD.
//     Real finding: OccupancyPercent=48 — grid 1024 blocks = only 4 blk/CU;
//     VGPR=60 would allow 8. The gather is latency-bound, so resident-wave
//     count is the lever.
// R10 (this): classic 4-dispatch, TILE 64->32 points => grid 2048 = 8 blk/CU,
//     __launch_bounds__(256,8) pins VGPR<=64. Predict occupancy ~2x, layer
//     kernels ~1.7-2x faster, total ~120-135 us.

#define NPTS 65536
#define KNBR 64
#define TILE 32

__device__ __forceinline__ float celu1(float x) {
    return x > 0.0f ? x : (__expf(x) - 1.0f);
}

__device__ __forceinline__ unsigned pkmax(unsigned a, unsigned b) {
    unsigned d;
    asm("v_pk_max_f16 %0, %1, %2" : "=v"(d) : "v"(a), "v"(b));
    return d;
}

__device__ __forceinline__ unsigned pack2(float a, float b) {
    __half2 h = __floats2half2_rn(a, b);
    return *(unsigned*)&h;
}

// prep: Q1 (fp16) from pos, pos copy to d_out, zero batch tail.
__global__ __launch_bounds__(256) void k_prep(
    const float* __restrict__ pos,
    const float* __restrict__ w1a,   // 6 x 8
    const float* __restrict__ b1a,   // 8
    __half* __restrict__ q1,         // N x 8 (fp16)
    float* __restrict__ dout,
    int out_size)
{
    int t = blockIdx.x * 256 + threadIdx.x;
    if (t >= NPTS) return;
    float p0 = pos[3 * t + 0];
    float p1 = pos[3 * t + 1];
    float p2 = pos[3 * t + 2];
    dout[3 * t + 0] = p0;
    dout[3 * t + 1] = p1;
    dout[3 * t + 2] = p2;
    float q[8];
#pragma unroll
    for (int c = 0; c < 8; ++c) {
        float a = b1a[c];
        a = fmaf(p0, w1a[0 * 8 + c] + w1a[3 * 8 + c], a);
        a = fmaf(p1, w1a[1 * 8 + c] + w1a[4 * 8 + c], a);
        a = fmaf(p2, w1a[2 * 8 + c] + w1a[5 * 8 + c], a);
        q[c] = a;
    }
    uint4 pk;
    pk.x = pack2(q[0], q[1]);
    pk.y = pack2(q[2], q[3]);
    pk.z = pack2(q[4], q[5]);
    pk.w = pack2(q[6], q[7]);
    *(uint4*)(q1 + 8 * t) = pk;
    for (int j = 35 * NPTS + t; j < out_size; j += NPTS)
        dout[j] = 0.0f;
}

// One fused layer: edge gather+max -> m staged in LDS -> per-point finish.
// Block = 256 threads = 4 waves, handles TILE=32 points. Grid = NPTS/TILE =
// 2048 blocks = 8 blocks/CU (occupancy 100% at VGPR<=64).
template <int FH, int FOUT, int FHN, bool WRITEX>
__global__ __launch_bounds__(256, 8) void k_layer(
    const __half* __restrict__ q,    // N x FH (fp16)
    const int* __restrict__ idx,     // N x 64 (int32)
    const float* __restrict__ pos,
    const float* __restrict__ wap,   // 3 x FH  (dpos rows of this layer's wa)
    const float* __restrict__ wb,    // FH x FOUT
    const float* __restrict__ bb,    // FOUT
    const float* __restrict__ wan,   // (FOUT+3) x FHN or null
    const float* __restrict__ ban,   // FHN or null
    float* __restrict__ xout,        // x region base (only if WRITEX)
    __half* __restrict__ qnext)      // N x FHN fp16 (only if FHN>0)
{
    constexpr int SL  = FH / 8;      // 16B slice-lanes per row (1,2,4)
    constexpr int LPP = SL * 8;      // lanes per point (8,16,32)
    constexpr int PPW = 64 / LPP;    // points per wave per iter (8,4,2)
    constexpr int NIT = TILE / (4 * PPW);  // iters so block covers TILE points

    __shared__ uint4 m_lds[TILE * SL]; // TILE points x FH halfs

    int w  = threadIdx.x >> 6;
    int l  = threadIdx.x & 63;
    int pl = l / LPP;
    int u  = l % LPP;
    int c  = u % SL;                 // 16B slice within row
    int g  = u / SL;                 // edge group 0..7 (8 edges each)
    int pbase = blockIdx.x * TILE;

#pragma unroll
    for (int it = 0; it < NIT; ++it) {
        int lp = it * (4 * PPW) + w * PPW + pl;   // local point 0..TILE-1
        int p  = pbase + lp;
        const uint4* ip = (const uint4*)(idx + p * KNBR + g * 8);
        uint4 i0 = ip[0];
        uint4 i1 = ip[1];
        // 8 independent row-slice loads, all issued before first use
        uint4 v[8];
        v[0] = *(const uint4*)(q + (int)i0.x * FH + c * 8);
        v[1] = *(const uint4*)(q + (int)i0.y * FH + c * 8);
        v[2] = *(const uint4*)(q + (int)i0.z * FH + c * 8);
        v[3] = *(const uint4*)(q + (int)i0.w * FH + c * 8);
        v[4] = *(const uint4*)(q + (int)i1.x * FH + c * 8);
        v[5] = *(const uint4*)(q + (int)i1.y * FH + c * 8);
        v[6] = *(const uint4*)(q + (int)i1.z * FH + c * 8);
        v[7] = *(const uint4*)(q + (int)i1.w * FH + c * 8);

        unsigned ax = 0xFC00FC00u, ay = 0xFC00FC00u, az = 0xFC00FC00u, aw = 0xFC00FC00u;
#pragma unroll
        for (int k = 0; k < 8; ++k) {
            ax = pkmax(ax, v[k].x);
            ay = pkmax(ay, v[k].y);
            az = pkmax(az, v[k].z);
            aw = pkmax(aw, v[k].w);
        }
        // butterfly across the 8 edge groups (strides SL..4SL stay in-point)
#pragma unroll
        for (int st = SL; st < LPP; st <<= 1) {
            ax = pkmax(ax, (unsigned)__shfl_xor((int)ax, st, 64));
            ay = pkmax(ay, (unsigned)__shfl_xor((int)ay, st, 64));
            az = pkmax(az, (unsigned)__shfl_xor((int)az, st, 64));
            aw = pkmax(aw, (unsigned)__shfl_xor((int)aw, st, 64));
        }
        if (g == 0) {
            uint4 r; r.x = ax; r.y = ay; r.z = az; r.w = aw;
            m_lds[lp * SL + c] = r;
        }
    }
    __syncthreads();

    if constexpr (WRITEX) {
        // Final layer: 4 lanes per point, each computes 8 of FOUT=32 outputs.
        // Keeps live floats ~= FH + 8 instead of FH + FOUT (VGPR cap 64).
        if (threadIdx.x < TILE * 4) {
            int pt  = threadIdx.x >> 2;
            int qtr = threadIdx.x & 3;
            int p   = pbase + pt;
            float p0 = pos[3 * p + 0];
            float p1 = pos[3 * p + 1];
            float p2 = pos[3 * p + 2];

            float h[FH];
#pragma unroll
            for (int s = 0; s < SL; ++s) {
                uint4 vv = m_lds[pt * SL + s];
                unsigned w4[4] = {vv.x, vv.y, vv.z, vv.w};
#pragma unroll
                for (int k = 0; k < 4; ++k) {
                    float2 f = __half22float2(*(__half2*)&w4[k]);
                    h[s * 8 + k * 2 + 0] = f.x;
                    h[s * 8 + k * 2 + 1] = f.y;
                }
            }
#pragma unroll
            for (int ch = 0; ch < FH; ++ch) {
                float gg = p0 * wap[ch] + p1 * wap[FH + ch] + p2 * wap[2 * FH + ch];
                h[ch] = celu1(h[ch] - gg);
            }
            float x[8];
#pragma unroll
            for (int j = 0; j < 8; ++j) {
                int c2 = qtr * 8 + j;
                float a = bb[c2];
#pragma unroll
                for (int ch = 0; ch < FH; ++ch)
                    a = fmaf(h[ch], wb[ch * FOUT + c2], a);
                x[j] = celu1(a);
            }
            float4* xo = (float4*)(xout + (long long)p * FOUT + qtr * 8);
            xo[0] = make_float4(x[0], x[1], x[2], x[3]);
            xo[1] = make_float4(x[4], x[5], x[6], x[7]);
        }
    } else if (threadIdx.x < TILE) {
        int lt = threadIdx.x;
        int p  = pbase + lt;
        float p0 = pos[3 * p + 0];
        float p1 = pos[3 * p + 1];
        float p2 = pos[3 * p + 2];

        float h[FH];
#pragma unroll
        for (int s = 0; s < SL; ++s) {
            uint4 vv = m_lds[lt * SL + s];
            unsigned w4[4] = {vv.x, vv.y, vv.z, vv.w};
#pragma unroll
            for (int k = 0; k < 4; ++k) {
                float2 f = __half22float2(*(__half2*)&w4[k]);
                h[s * 8 + k * 2 + 0] = f.x;
                h[s * 8 + k * 2 + 1] = f.y;
            }
        }
#pragma unroll
        for (int ch = 0; ch < FH; ++ch) {
            float gg = p0 * wap[ch] + p1 * wap[FH + ch] + p2 * wap[2 * FH + ch];
            h[ch] = celu1(h[ch] - gg);
        }
        float x[FOUT];
#pragma unroll
        for (int c2 = 0; c2 < FOUT; ++c2) {
            float a = bb[c2];
#pragma unroll
            for (int ch = 0; ch < FH; ++ch)
                a = fmaf(h[ch], wb[ch * FOUT + c2], a);
            x[c2] = celu1(a);
        }
        if constexpr (FHN > 0) {
            // qnext packed 8-at-a-time: peak live floats = FOUT + 8.
            uint4* qo = (uint4*)(qnext + p * FHN);
#pragma unroll
            for (int s = 0; s < FHN / 8; ++s) {
                float qn[8];
#pragma unroll
                for (int k = 0; k < 8; ++k) {
                    int cn = s * 8 + k;
                    float a = ban[cn];
#pragma unroll
                    for (int c2 = 0; c2 < FOUT; ++c2)
                        a = fmaf(x[c2], wan[c2 * FHN + cn], a);
                    a = fmaf(p0, wan[(FOUT + 0) * FHN + cn], a);
                    a = fmaf(p1, wan[(FOUT + 1) * FHN + cn], a);
                    a = fmaf(p2, wan[(FOUT + 2) * FHN + cn], a);
                    qn[k] = a;
                }
                uint4 pk;
                pk.x = pack2(qn[0], qn[1]);
                pk.y = pack2(qn[2], qn[3]);
                pk.z = pack2(qn[4], qn[5]);
                pk.w = pack2(qn[6], qn[7]);
                qo[s] = pk;
            }
        }
    }
}

extern "C" void kernel_launch(void* const* d_in, const int* in_sizes, int n_in,
                              void* d_out, int out_size, void* d_ws, size_t ws_size,
                              hipStream_t stream) {
    const float* pos = (const float*)d_in[0];
    // d_in[1] rgb (unused), d_in[2] batch (zeros), d_in[3] out_index (= repeat(arange(N),K))
    const int* idx = (const int*)d_in[4];   // in_index, int32 per harness contract
    const float* w1a = (const float*)d_in[5];
    const float* b1a = (const float*)d_in[6];
    const float* w1b = (const float*)d_in[7];
    const float* b1b = (const float*)d_in[8];
    const float* w2a = (const float*)d_in[9];
    const float* b2a = (const float*)d_in[10];
    const float* w2b = (const float*)d_in[11];
    const float* b2b = (const float*)d_in[12];
    const float* w3a = (const float*)d_in[13];
    const float* b3a = (const float*)d_in[14];
    const float* w3b = (const float*)d_in[15];
    const float* b3b = (const float*)d_in[16];
    float* out = (float*)d_out;

    char* ws = (char*)d_ws;
    __half* A = (__half*)ws;                        // 4 MB max: Q1 (1MB) then Q3 (4MB)
    __half* B = (__half*)(ws + (4u << 20));         // 2 MB: Q2

    k_prep<<<NPTS / 256, 256, 0, stream>>>(pos, w1a, b1a, A, out, out_size);
    // layer 1: FH=8 -> FOUT=8, emits Q2 (16ch) into B
    k_layer<8, 8, 16, false><<<NPTS / TILE, 256, 0, stream>>>(
        A, idx, pos, w1a + 3 * 8, w1b, b1b, w2a, b2a, nullptr, B);
    // layer 2: FH=16 -> FOUT=16, emits Q3 (32ch) into A
    k_layer<16, 16, 32, false><<<NPTS / TILE, 256, 0, stream>>>(
        B, idx, pos, w2a + 8 * 16, w2b, b2b, w3a, b3a, nullptr, A);
    // layer 3: FH=32 -> FOUT=32, writes final x into d_out
    k_layer<32, 32, 0, true><<<NPTS / TILE, 256, 0, stream>>>(
        A, idx, pos, w3a + 16 * 32, w3b, b3b, nullptr, nullptr, out + 3 * NPTS, nullptr);
}

// Round 4
// 177.221 us; speedup vs baseline: 2.1049x; 1.0042x over previous
//
#include <hip/hip_runtime.h>
#include <hip/hip_fp16.h>
#include <math.h>

// SPAIRPointFeatureNetwork on MI355X.
//   h_{p,j} = Q[j] - G[p];  celu monotonic => segmax(celu(h)) = celu(max_j Q[j] - G[p]).
// Per-edge work = gather fp16 Q row + packed-fp16 running max.
//
// R9: coop mega = 439us, grid.sync ~80-100us each. Coop dead. VALUBusy 3%,
//     HBM 2.6% => gather path is ~90% stall.
// R10: 8 blk/CU (2x occupancy) EXACTLY neutral => not latency-bound; shared
//     per-CU L1-miss throughput on random gathers is the limiter
//     (4.19M random lines/layer; pts in random memory order).
// R11 (this): spatial cell-sort once per launch (16^3 grid), Q/pos stored
//     sorted, idx translated to new ids once. A 32-pt tile then gathers from
//     ~430 distinct rows (<=27KB) => ~5x miss reduction. CU-contiguity
//     swizzle ((b&255)*8+(b>>8)) gives the 8 co-resident blocks one sliding
//     window. Output bit-identical (max order-independent; scatter back via
//     order[]). Infra: memset+cell+scan+scatter+translate ~30-40us.
//     Predict 177 -> ~125-145us.

#define NPTS 65536
#define KNBR 64
#define TILE 32
#define NCELL 4096

__device__ __forceinline__ float celu1(float x) {
    return x > 0.0f ? x : (__expf(x) - 1.0f);
}

__device__ __forceinline__ unsigned pkmax(unsigned a, unsigned b) {
    unsigned d;
    asm("v_pk_max_f16 %0, %1, %2" : "=v"(d) : "v"(a), "v"(b));
    return d;
}

__device__ __forceinline__ unsigned pack2(float a, float b) {
    __half2 h = __floats2half2_rn(a, b);
    return *(unsigned*)&h;
}

// ---- sort infra -----------------------------------------------------------

// cell id per point + histogram; also pos->out copy and tail zero.
__global__ __launch_bounds__(256) void k_cell(
    const float* __restrict__ pos, float* __restrict__ dout, int out_size,
    int* __restrict__ cid, int* __restrict__ hist)
{
    int t = blockIdx.x * 256 + threadIdx.x;
    if (t < NPTS) {
        float p0 = pos[3 * t + 0];
        float p1 = pos[3 * t + 1];
        float p2 = pos[3 * t + 2];
        dout[3 * t + 0] = p0;
        dout[3 * t + 1] = p1;
        dout[3 * t + 2] = p2;
        int cx = min((int)(p0 * 16.0f), 15);
        int cy = min((int)(p1 * 16.0f), 15);
        int cz = min((int)(p2 * 16.0f), 15);
        int c = (cx * 16 + cy) * 16 + cz;
        cid[t] = c;
        atomicAdd(&hist[c], 1);
        for (int j = 35 * NPTS + t; j < out_size; j += NPTS)
            dout[j] = 0.0f;
    }
}

// exclusive scan of hist[4096] -> cellptr. One wave.
__global__ __launch_bounds__(64) void k_scan(
    const int* __restrict__ hist, int* __restrict__ cellptr)
{
    int l = threadIdx.x;              // 0..63, owns cells l*64..l*64+63
    int v[64];
    int s = 0;
#pragma unroll
    for (int i = 0; i < 64; ++i) { v[i] = s; s += hist[l * 64 + i]; }
    int run = s;
#pragma unroll
    for (int st = 1; st < 64; st <<= 1) {
        int o = __shfl_up(run, st, 64);
        if (l >= st) run += o;
    }
    int off = run - s;                // exclusive prefix of this chunk
#pragma unroll
    for (int i = 0; i < 64; ++i)
        cellptr[l * 64 + i] = off + v[i];
}

// scatter: assign new ids, build perm/order, sorted pos, sorted Q1 (prep fold).
__global__ __launch_bounds__(256) void k_scatter(
    const float* __restrict__ pos, const int* __restrict__ cid,
    int* __restrict__ cellptr, unsigned short* __restrict__ perm,
    int* __restrict__ order, float* __restrict__ pos_s,
    const float* __restrict__ w1a, const float* __restrict__ b1a,
    __half* __restrict__ q1s)
{
    int t = blockIdx.x * 256 + threadIdx.x;
    if (t >= NPTS) return;
    int c = cid[t];
    int nid = atomicAdd(&cellptr[c], 1);
    perm[t] = (unsigned short)nid;
    order[nid] = t;
    float p0 = pos[3 * t + 0];
    float p1 = pos[3 * t + 1];
    float p2 = pos[3 * t + 2];
    pos_s[3 * nid + 0] = p0;
    pos_s[3 * nid + 1] = p1;
    pos_s[3 * nid + 2] = p2;
    float q[8];
#pragma unroll
    for (int ch = 0; ch < 8; ++ch) {
        float a = b1a[ch];
        a = fmaf(p0, w1a[0 * 8 + ch] + w1a[3 * 8 + ch], a);
        a = fmaf(p1, w1a[1 * 8 + ch] + w1a[4 * 8 + ch], a);
        a = fmaf(p2, w1a[2 * 8 + ch] + w1a[5 * 8 + ch], a);
        q[ch] = a;
    }
    uint4 pk;
    pk.x = pack2(q[0], q[1]);
    pk.y = pack2(q[2], q[3]);
    pk.z = pack2(q[4], q[5]);
    pk.w = pack2(q[6], q[7]);
    *(uint4*)(q1s + 8 * nid) = pk;
}

// translate neighbor ids to sorted space: idxs[p][k] = perm[idx[order[p]][k]].
__global__ __launch_bounds__(256) void k_trans(
    const int* __restrict__ idx, const int* __restrict__ order,
    const unsigned short* __restrict__ perm, int* __restrict__ idxs)
{
    int g = blockIdx.x * 256 + threadIdx.x;   // NPTS*16 threads, 4 edges each
    int row = g >> 4;
    int j = g & 15;
    int old = order[row];
    int4 v = *(const int4*)(idx + old * KNBR + j * 4);
    int4 o;
    o.x = perm[v.x];
    o.y = perm[v.y];
    o.z = perm[v.z];
    o.w = perm[v.w];
    *(int4*)(idxs + row * KNBR + j * 4) = o;
}

// ---- fused layer (sorted space) ------------------------------------------
// Block = 256 threads = 4 waves, TILE=32 sorted points. Grid 2048 = 8 blk/CU.
// Tile swizzle: dispatch->CU round-robins with stride ~256, so give stride-256
// blocks consecutive tiles => one CU's 8 blocks share a 256-point window.
template <int FH, int FOUT, int FHN, bool WRITEX>
__global__ __launch_bounds__(256, 8) void k_layer(
    const __half* __restrict__ q,    // N x FH (fp16, sorted)
    const int* __restrict__ idx,     // N x 64 (int32, sorted ids)
    const float* __restrict__ pos,   // sorted pos
    const int* __restrict__ order,   // new->old (only used if WRITEX)
    const float* __restrict__ wap,   // 3 x FH  (dpos rows of this layer's wa)
    const float* __restrict__ wb,    // FH x FOUT
    const float* __restrict__ bb,    // FOUT
    const float* __restrict__ wan,   // (FOUT+3) x FHN or null
    const float* __restrict__ ban,   // FHN or null
    float* __restrict__ xout,        // x region base (only if WRITEX)
    __half* __restrict__ qnext)      // N x FHN fp16 (only if FHN>0)
{
    constexpr int SL  = FH / 8;      // 16B slice-lanes per row (1,2,4)
    constexpr int LPP = SL * 8;      // lanes per point (8,16,32)
    constexpr int PPW = 64 / LPP;    // points per wave per iter (8,4,2)
    constexpr int NIT = TILE / (4 * PPW);

    __shared__ uint4 m_lds[TILE * SL];

    int w  = threadIdx.x >> 6;
    int l  = threadIdx.x & 63;
    int pl = l / LPP;
    int u  = l % LPP;
    int c  = u % SL;
    int g  = u / SL;
    int tb = (blockIdx.x & 255) * (NPTS / TILE / 256) + (blockIdx.x >> 8);
    int pbase = tb * TILE;

#pragma unroll
    for (int it = 0; it < NIT; ++it) {
        int lp = it * (4 * PPW) + w * PPW + pl;
        int p  = pbase + lp;
        const uint4* ip = (const uint4*)(idx + p * KNBR + g * 8);
        uint4 i0 = ip[0];
        uint4 i1 = ip[1];
        uint4 v[8];
        v[0] = *(const uint4*)(q + (int)i0.x * FH + c * 8);
        v[1] = *(const uint4*)(q + (int)i0.y * FH + c * 8);
        v[2] = *(const uint4*)(q + (int)i0.z * FH + c * 8);
        v[3] = *(const uint4*)(q + (int)i0.w * FH + c * 8);
        v[4] = *(const uint4*)(q + (int)i1.x * FH + c * 8);
        v[5] = *(const uint4*)(q + (int)i1.y * FH + c * 8);
        v[6] = *(const uint4*)(q + (int)i1.z * FH + c * 8);
        v[7] = *(const uint4*)(q + (int)i1.w * FH + c * 8);

        unsigned ax = 0xFC00FC00u, ay = 0xFC00FC00u, az = 0xFC00FC00u, aw = 0xFC00FC00u;
#pragma unroll
        for (int k = 0; k < 8; ++k) {
            ax = pkmax(ax, v[k].x);
            ay = pkmax(ay, v[k].y);
            az = pkmax(az, v[k].z);
            aw = pkmax(aw, v[k].w);
        }
#pragma unroll
        for (int st = SL; st < LPP; st <<= 1) {
            ax = pkmax(ax, (unsigned)__shfl_xor((int)ax, st, 64));
            ay = pkmax(ay, (unsigned)__shfl_xor((int)ay, st, 64));
            az = pkmax(az, (unsigned)__shfl_xor((int)az, st, 64));
            aw = pkmax(aw, (unsigned)__shfl_xor((int)aw, st, 64));
        }
        if (g == 0) {
            uint4 r; r.x = ax; r.y = ay; r.z = az; r.w = aw;
            m_lds[lp * SL + c] = r;
        }
    }
    __syncthreads();

    if constexpr (WRITEX) {
        // 4 lanes per point, 8 of FOUT=32 outputs each (VGPR cap 64).
        if (threadIdx.x < TILE * 4) {
            int pt  = threadIdx.x >> 2;
            int qtr = threadIdx.x & 3;
            int p   = pbase + pt;
            float p0 = pos[3 * p + 0];
            float p1 = pos[3 * p + 1];
            float p2 = pos[3 * p + 2];

            float h[FH];
#pragma unroll
            for (int s = 0; s < SL; ++s) {
                uint4 vv = m_lds[pt * SL + s];
                unsigned w4[4] = {vv.x, vv.y, vv.z, vv.w};
#pragma unroll
                for (int k = 0; k < 4; ++k) {
                    float2 f = __half22float2(*(__half2*)&w4[k]);
                    h[s * 8 + k * 2 + 0] = f.x;
                    h[s * 8 + k * 2 + 1] = f.y;
                }
            }
#pragma unroll
            for (int ch = 0; ch < FH; ++ch) {
                float gg = p0 * wap[ch] + p1 * wap[FH + ch] + p2 * wap[2 * FH + ch];
                h[ch] = celu1(h[ch] - gg);
            }
            float x[8];
#pragma unroll
            for (int j = 0; j < 8; ++j) {
                int c2 = qtr * 8 + j;
                float a = bb[c2];
#pragma unroll
                for (int ch = 0; ch < FH; ++ch)
                    a = fmaf(h[ch], wb[ch * FOUT + c2], a);
                x[j] = celu1(a);
            }
            int oldp = order[p];
            float4* xo = (float4*)(xout + (long long)oldp * FOUT + qtr * 8);
            xo[0] = make_float4(x[0], x[1], x[2], x[3]);
            xo[1] = make_float4(x[4], x[5], x[6], x[7]);
        }
    } else if (threadIdx.x < TILE) {
        int lt = threadIdx.x;
        int p  = pbase + lt;
        float p0 = pos[3 * p + 0];
        float p1 = pos[3 * p + 1];
        float p2 = pos[3 * p + 2];

        float h[FH];
#pragma unroll
        for (int s = 0; s < SL; ++s) {
            uint4 vv = m_lds[lt * SL + s];
            unsigned w4[4] = {vv.x, vv.y, vv.z, vv.w};
#pragma unroll
            for (int k = 0; k < 4; ++k) {
                float2 f = __half22float2(*(__half2*)&w4[k]);
                h[s * 8 + k * 2 + 0] = f.x;
                h[s * 8 + k * 2 + 1] = f.y;
            }
        }
#pragma unroll
        for (int ch = 0; ch < FH; ++ch) {
            float gg = p0 * wap[ch] + p1 * wap[FH + ch] + p2 * wap[2 * FH + ch];
            h[ch] = celu1(h[ch] - gg);
        }
        float x[FOUT];
#pragma unroll
        for (int c2 = 0; c2 < FOUT; ++c2) {
            float a = bb[c2];
#pragma unroll
            for (int ch = 0; ch < FH; ++ch)
                a = fmaf(h[ch], wb[ch * FOUT + c2], a);
            x[c2] = celu1(a);
        }
        if constexpr (FHN > 0) {
            uint4* qo = (uint4*)(qnext + p * FHN);
#pragma unroll
            for (int s = 0; s < FHN / 8; ++s) {
                float qn[8];
#pragma unroll
                for (int k = 0; k < 8; ++k) {
                    int cn = s * 8 + k;
                    float a = ban[cn];
#pragma unroll
                    for (int c2 = 0; c2 < FOUT; ++c2)
                        a = fmaf(x[c2], wan[c2 * FHN + cn], a);
                    a = fmaf(p0, wan[(FOUT + 0) * FHN + cn], a);
                    a = fmaf(p1, wan[(FOUT + 1) * FHN + cn], a);
                    a = fmaf(p2, wan[(FOUT + 2) * FHN + cn], a);
                    qn[k] = a;
                }
                uint4 pk;
                pk.x = pack2(qn[0], qn[1]);
                pk.y = pack2(qn[2], qn[3]);
                pk.z = pack2(qn[4], qn[5]);
                pk.w = pack2(qn[6], qn[7]);
                qo[s] = pk;
            }
        }
    }
}

extern "C" void kernel_launch(void* const* d_in, const int* in_sizes, int n_in,
                              void* d_out, int out_size, void* d_ws, size_t ws_size,
                              hipStream_t stream) {
    const float* pos = (const float*)d_in[0];
    // d_in[1] rgb (unused), d_in[2] batch (zeros), d_in[3] out_index
    const int* idx = (const int*)d_in[4];   // in_index, int32
    const float* w1a = (const float*)d_in[5];
    const float* b1a = (const float*)d_in[6];
    const float* w1b = (const float*)d_in[7];
    const float* b1b = (const float*)d_in[8];
    const float* w2a = (const float*)d_in[9];
    const float* b2a = (const float*)d_in[10];
    const float* w2b = (const float*)d_in[11];
    const float* b2b = (const float*)d_in[12];
    const float* w3a = (const float*)d_in[13];
    const float* b3a = (const float*)d_in[14];
    const float* w3b = (const float*)d_in[15];
    const float* b3b = (const float*)d_in[16];
    float* out = (float*)d_out;

    char* ws = (char*)d_ws;
    __half* A      = (__half*)ws;                       // q1s (1MB) then q3s (4MB)
    __half* B      = (__half*)(ws + (4u << 20));        // q2s (2MB)
    int*    idxs   = (int*)(ws + (8u << 20));           // 16MB translated idx
    int*    cid    = (int*)(ws + (24u << 20));          // 256KB
    int*    order  = (int*)(ws + (25u << 20));          // 256KB
    unsigned short* perm = (unsigned short*)(ws + (26u << 20)); // 128KB
    int*    hist   = (int*)(ws + (27u << 20));          // 16KB
    int*    cellptr= (int*)(ws + (27u << 20) + (64u << 10));    // 16KB
    float*  pos_s  = (float*)(ws + (28u << 20));        // 768KB

    hipMemsetAsync(hist, 0, NCELL * sizeof(int), stream);
    k_cell<<<NPTS / 256, 256, 0, stream>>>(pos, out, out_size, cid, hist);
    k_scan<<<1, 64, 0, stream>>>(hist, cellptr);
    k_scatter<<<NPTS / 256, 256, 0, stream>>>(pos, cid, cellptr, perm, order,
                                              pos_s, w1a, b1a, A);
    k_trans<<<NPTS * 16 / 256, 256, 0, stream>>>(idx, order, perm, idxs);

    // layer 1: FH=8 -> FOUT=8, emits Q2 (16ch) into B
    k_layer<8, 8, 16, false><<<NPTS / TILE, 256, 0, stream>>>(
        A, idxs, pos_s, nullptr, w1a + 3 * 8, w1b, b1b, w2a, b2a, nullptr, B);
    // layer 2: FH=16 -> FOUT=16, emits Q3 (32ch) into A
    k_layer<16, 16, 32, false><<<NPTS / TILE, 256, 0, stream>>>(
        B, idxs, pos_s, nullptr, w2a + 8 * 16, w2b, b2b, w3a, b3a, nullptr, A);
    // layer 3: FH=32 -> FOUT=32, writes final x into d_out (old-id rows)
    k_layer<32, 32, 0, true><<<NPTS / TILE, 256, 0, stream>>>(
        A, idxs, pos_s, order, w3a + 16 * 32, w3b, b3b, nullptr, nullptr,
        out + 3 * NPTS, nullptr);
}